// Round 11
// baseline (98.346 us; speedup 1.0000x reference)
//
#include <hip/hip_runtime.h>
#include <math.h>

// Problem constants (match reference setup_inputs)
constexpr int B = 2;
constexpr int N = 4096;
constexpr int C = 32;
constexpr int D = 256;
constexpr int K = 16;
constexpr int NW = N / 32;   // adjacency bitmask words per row = 128
constexpr int CAP = 128;     // max neighbors per row (16 out + in-degree)
constexpr int ROWS = B * N;  // 8192

// ---------------------------------------------------------------------------
// Kernel 1: per-row preprocess: centers(+sqnorm or INF if invalid), feature
// inv-norm. One wave (64 lanes) per row. Also zeroes the adjacency bitmask.
__global__ void pre_kernel(const float* __restrict__ rois,
                           const float* __restrict__ feats,
                           float4* __restrict__ centers4,
                           float* __restrict__ invnorm,
                           uint2* __restrict__ adj_zero) {
    const int t = threadIdx.x;
    const int wid = t >> 6, lane = t & 63;
    const int r = blockIdx.x * 4 + wid;

    // zero adjacency: 2048 blocks * 256 threads == ROWS*NW/2 uint2 elements
    adj_zero[blockIdx.x * 256 + t] = make_uint2(0u, 0u);

    if (r >= ROWS) return;

    const float4* f4 = reinterpret_cast<const float4*>(feats) + (size_t)r * (D / 4);
    float4 v = f4[lane];
    float ss = v.x * v.x + v.y * v.y + v.z * v.z + v.w * v.w;
#pragma unroll
    for (int off = 32; off; off >>= 1) ss += __shfl_xor(ss, off);

    if (lane == 0) {
        invnorm[r] = 1.0f / fmaxf(sqrtf(ss), 1e-6f);
        const float* rp = rois + (size_t)r * 6;
        float a0 = rp[0], a1 = rp[1], a2 = rp[2], a3 = rp[3], a4 = rp[4], a5 = rp[5];
        float cx = (a0 + a3) * 0.5f, cy = (a1 + a4) * 0.5f, cz = (a2 + a5) * 0.5f;
        float sq = cx * cx + cy * cy + cz * cz;
        float s = fabsf(a0) + fabsf(a1) + fabsf(a2) + fabsf(a3) + fabsf(a4) + fabsf(a5);
        centers4[r] = make_float4(cx, cy, cz, (s > 0.0f) ? sq : INFINITY);
    }
}

// ---------------------------------------------------------------------------
// Kernel 2: exact 16-NN, chunk-in-register structure (see R8 notes).
__global__ __launch_bounds__(1024, 8) void knn_kernel(const float4* __restrict__ centers4,
                                                      unsigned* __restrict__ adj) {
    __shared__ float4 s_c[N];                        // 64 KB
    __shared__ unsigned s_pm[16][64];                // 4 KB subset-min bits
    __shared__ unsigned long long s_buf[16][64];     // 8 KB survivor keys
    __shared__ int s_cnt[16];
    __shared__ float s_tau[16];

    const int t = threadIdx.x;
    const int lane = t & 63;
    const int wv = t >> 6;
    const int r0 = blockIdx.x * 16;        // first global row of block
    const int nbase = r0 & (N - 1);        // first in-batch row index
    const int gbase = r0 - nbase;          // batch offset (0 or N)

    if (t < 16) s_cnt[t] = 0;
    ((unsigned*)s_pm)[t] = 0x7F800000u;    // +INF bits (1024 entries exactly)
    for (int i = t; i < N; i += 1024) s_c[i] = centers4[gbase + i];
    __syncthreads();

    // wave-owned candidate chunk, kept in registers
    float4 cmv[4];
    int    mv[4];
#pragma unroll
    for (int u = 0; u < 4; ++u) {
        mv[u] = (wv << 8) + (u << 6) + lane;
        cmv[u] = s_c[mv[u]];
    }

    // ---- pass 1: per-row min over this lane's 4 candidates; merge via atomicMin ----
#pragma unroll 4
    for (int rr = 0; rr < 16; ++rr) {
        const int nrow = nbase + rr;
        const float4 rc = s_c[nrow];       // same-address broadcast, conflict-free
        float mn = INFINITY;
#pragma unroll
        for (int u = 0; u < 4; ++u) {
            float dist = fmaxf(rc.w + cmv[u].w -
                               2.0f * (rc.x * cmv[u].x + rc.y * cmv[u].y + rc.z * cmv[u].z), 0.0f);
            mn = fminf(mn, (mv[u] == nrow) ? INFINITY : dist);
        }
        atomicMin(&s_pm[rr][lane], __float_as_uint(mn));
    }
    __syncthreads();

    // ---- tau per row: wave rr sorts its row's 64 subset minima ----
    {
        float v = __uint_as_float(s_pm[wv][lane]);
#pragma unroll
        for (int k = 2; k <= 64; k <<= 1) {
#pragma unroll
            for (int j = k >> 1; j > 0; j >>= 1) {
                float o = __shfl_xor(v, j);
                bool take_min = (((lane & j) == 0) == ((lane & k) == 0));
                v = take_min ? fminf(v, o) : fmaxf(v, o);
            }
        }
        if (lane == 15) s_tau[wv] = v;     // 16th smallest
    }
    __syncthreads();

    // ---- pass 2: append survivors from the register chunk for all 16 rows ----
#pragma unroll 4
    for (int rr = 0; rr < 16; ++rr) {
        const int nrow = nbase + rr;
        const float tau = s_tau[rr];
        const float4 rc = s_c[nrow];
#pragma unroll
        for (int u = 0; u < 4; ++u) {
            float dist = fmaxf(rc.w + cmv[u].w -
                               2.0f * (rc.x * cmv[u].x + rc.y * cmv[u].y + rc.z * cmv[u].z), 0.0f);
            if (dist <= tau && mv[u] != nrow) {
                int pos = atomicAdd(&s_cnt[rr], 1);
                if (pos < 64)
                    s_buf[rr][pos] = ((unsigned long long)__float_as_uint(dist) << 32)
                                     | (unsigned)mv[u];
            }
        }
    }
    __syncthreads();

    // ---- selection: wave rr owns row rr ----
    const int rg = r0 + wv;                // global row
    const int n = nbase + wv;              // in-batch row
    const int cnt = s_cnt[wv];

    int my_sel = -1;
    if (cnt <= 64) {
        unsigned long long key = (lane < cnt) ? s_buf[wv][lane] : ~0ull;
#pragma unroll
        for (int k = 2; k <= 64; k <<= 1) {
#pragma unroll
            for (int j = k >> 1; j > 0; j >>= 1) {
                unsigned long long o = __shfl_xor(key, j);
                bool take_min = (((lane & j) == 0) == ((lane & k) == 0));
                unsigned long long mn = (key < o) ? key : o;
                unsigned long long mx = (key < o) ? o : key;
                key = take_min ? mn : mx;
            }
        }
        if (lane < K && key != ~0ull) my_sel = (int)(unsigned)key;
    } else {
        // exact fallback: 16 rounds of full rescan-argmin over LDS table
        const float4 cq = s_c[n];
        unsigned long long removed = 0ull;
        for (int round = 0; round < K; ++round) {
            float bd = INFINITY; int bi = 0x7FFFFFFF;
            for (int j = 0; j < 64; ++j) {
                const int m = lane + (j << 6);
                float4 cm = s_c[m];
                float dist = fmaxf(cq.w + cm.w -
                                   2.0f * (cq.x * cm.x + cq.y * cm.y + cq.z * cm.z), 0.0f);
                bool skip = ((removed >> j) & 1ull) || (m == n);
                if (!skip && dist < bd) { bd = dist; bi = m; }
            }
            float md = bd;
#pragma unroll
            for (int off = 32; off; off >>= 1) md = fminf(md, __shfl_xor(md, off));
            if (md == INFINITY) break;
            int kk = (bd == md) ? bi : 0x7FFFFFFF;
#pragma unroll
            for (int off = 32; off; off >>= 1) kk = min(kk, __shfl_xor(kk, off));
            if (lane == round) my_sel = kk;
            if (kk == bi) removed |= 1ull << (bi >> 6);
        }
    }

    if (my_sel >= 0) {
        atomicOr(&adj[(size_t)rg * NW + (my_sel >> 5)], 1u << (my_sel & 31));
        atomicOr(&adj[(size_t)(gbase + my_sel) * NW + (n >> 5)], 1u << (n & 31));
    }
}

// ---------------------------------------------------------------------------
// Kernel 3: build weighted neighbor lists from adjacency bits. One 512-thread
// block (8 waves) per row. Parallel popcount-prefix, then the cosine-dot
// phase: one wave per neighbor, 2-deep software pipeline (next neighbor's
// fm/cm/invnorm loads issued before reducing the current one; cm/invnorm are
// same-address broadcasts hoisted off the lane-0 critical path). Fused:
// lanes <32 compute initial softmax MOMENTS mu0 = (sum c*q, sum c^2*q)/s0.
__global__ __launch_bounds__(512) void build_kernel(const float* __restrict__ feats,
                             const float4* __restrict__ centers4,
                             const float* __restrict__ invnorm,
                             const unsigned* __restrict__ adj,
                             uint2* __restrict__ nbr,
                             int* __restrict__ nbr_cnt,
                             const float* __restrict__ raw_sigma,
                             const float* __restrict__ logits,
                             float2* __restrict__ mu0) {
    const int t = threadIdx.x;
    const int lane = t & 63;
    const int wv = t >> 6;          // 0..7
    const int r = blockIdx.x;
    const int base = r - (r & (N - 1));

    __shared__ int    s_off[NW];
    __shared__ int    s_wtot[2];
    __shared__ int    s_list[CAP];
    __shared__ float  s_w[CAP];
    __shared__ float4 s_fq[D / 4];
    __shared__ float  s_fsum[8];

    const float4* feats4 = reinterpret_cast<const float4*>(feats);
    if (t < D / 4) s_fq[t] = feats4[(size_t)r * (D / 4) + t];

    unsigned word = 0; int pc = 0;
    if (t < NW) {
        word = adj[(size_t)r * NW + t];
        pc = __popc(word);
    }
    int sc = pc;
#pragma unroll
    for (int off = 1; off < 64; off <<= 1) {
        int o = __shfl_up(sc, off);
        if (lane >= off) sc += o;
    }
    if (t < NW && lane == 63) s_wtot[wv] = sc;
    __syncthreads();
    const int total = s_wtot[0] + s_wtot[1];
    const int cnt = total > CAP ? CAP : total;
    if (t < NW) s_off[t] = sc - pc + ((wv == 1) ? s_wtot[0] : 0);
    __syncthreads();

    if (t < NW && word) {
        int o = s_off[t];
        unsigned w2 = word;
        while (w2) {
            int bit = __ffs(w2) - 1;
            if (o < CAP) s_list[o] = t * 32 + bit;
            ++o;
            w2 &= w2 - 1;
        }
    }
    __syncthreads();

    const float rs = raw_sigma[0];
    const float sigma = fmaxf(log1pf(expf(rs)), 1e-6f);
    const float nhalf_inv_s2 = -0.5f / (sigma * sigma);

    const float inq = invnorm[r];
    const float4 cq = centers4[r];

    // ---- neighbor weights: wave wv handles i = wv, wv+8, ... (2-deep pipeline)
    {
        int i = wv;
        float4 fm = make_float4(0, 0, 0, 0), cm = make_float4(0, 0, 0, 0);
        float inm = 0.0f;
        if (i < cnt) {
            int gm = base + s_list[i];
            fm = feats4[(size_t)gm * (D / 4) + lane];
            cm = centers4[gm];        // same-address broadcast across the wave
            inm = invnorm[gm];
        }
        while (i < cnt) {
            const int inxt = i + 8;
            float4 fm2 = make_float4(0, 0, 0, 0), cm2 = make_float4(0, 0, 0, 0);
            float inm2 = 0.0f;
            if (inxt < cnt) {
                int gm2 = base + s_list[inxt];
                fm2 = feats4[(size_t)gm2 * (D / 4) + lane];
                cm2 = centers4[gm2];
                inm2 = invnorm[gm2];
            }
            float4 fq = s_fq[lane];
            float p = fm.x * fq.x + fm.y * fq.y + fm.z * fq.z + fm.w * fq.w;
#pragma unroll
            for (int off = 32; off; off >>= 1) p += __shfl_xor(p, off);
            float cosv = p * inq * inm;
            float aff = fminf(fmaxf((cosv + 1.0f) * 0.5f, 0.0f), 1.0f);
            float dist = fmaxf(cq.w + cm.w -
                               2.0f * (cq.x * cm.x + cq.y * cm.y + cq.z * cm.z), 0.0f);
            if (lane == 0) s_w[i] = expf(dist * nhalf_inv_s2) * aff;
            i = inxt; fm = fm2; cm = cm2; inm = inm2;
        }
    }
    __syncthreads();

    // wave-parallel weight sum (deterministic)
    float ps = 0.0f;
    for (int i = t; i < cnt; i += 512) ps += s_w[i];
#pragma unroll
    for (int off = 32; off; off >>= 1) ps += __shfl_xor(ps, off);
    if (lane == 0) s_fsum[wv] = ps;
    __syncthreads();
    const float inv_sum = 1.0f / fmaxf(s_fsum[0] + s_fsum[1] + s_fsum[2] + s_fsum[3] +
                                       s_fsum[4] + s_fsum[5] + s_fsum[6] + s_fsum[7], 1e-6f);

    for (int i = t; i < cnt; i += 512) {
        nbr[(size_t)r * CAP + i] = make_uint2((unsigned)s_list[i],
                                              __float_as_uint(s_w[i] * inv_sum));
    }
    if (t == 0) nbr_cnt[r] = cnt;

    // fused initial softmax moments for this row (lanes 0..31)
    if (t < C) {
        float x = logits[(size_t)r * C + t];
        float mx = x;
#pragma unroll
        for (int off = 16; off; off >>= 1) mx = fmaxf(mx, __shfl_xor(mx, off, 32));
        float e = expf(x - mx);
        const float fc = (float)t;
        float s0 = e, s1 = e * fc, s2 = e * fc * fc;
#pragma unroll
        for (int off = 16; off; off >>= 1) {
            s0 += __shfl_xor(s0, off, 32);
            s1 += __shfl_xor(s1, off, 32);
            s2 += __shfl_xor(s2, off, 32);
        }
        if (t == 0) mu0[r] = make_float2(s1 / s0, s2 / s0);
    }
}

// ---------------------------------------------------------------------------
// Kernel 4: one mean-field iteration, MOMENT-COMPRESSED (see R9 notes).
__global__ void iter_kernel(const float* __restrict__ logits,
                            const uint2* __restrict__ nbr,
                            const int* __restrict__ nbr_cnt,
                            const float2* __restrict__ mu_in,
                            float2* __restrict__ mu_out,
                            float* __restrict__ out,
                            const float* __restrict__ raw_smooth,
                            int last) {
    const int t = threadIdx.x;
    const int r = blockIdx.x * 8 + (t >> 5);
    const int c = t & 31;
    const int base = r - (r & (N - 1));
    const float smooth = log1pf(expf(raw_smooth[0]));

    const int cnt = nbr_cnt[r];
    const uint2* np = nbr + (size_t)r * CAP;

    float m0 = 0.0f, m1 = 0.0f, m2 = 0.0f;
    for (int j = c; j < cnt; j += 32) {
        uint2 e = np[j];
        float w = __uint_as_float(e.y);
        float2 mu = mu_in[base + (int)e.x];
        m0 += w;
        m1 += w * mu.x;
        m2 += w * mu.y;
    }
#pragma unroll
    for (int off = 16; off; off >>= 1) {
        m0 += __shfl_xor(m0, off, 32);
        m1 += __shfl_xor(m1, off, 32);
        m2 += __shfl_xor(m2, off, 32);
    }

    const float fc = (float)c;
    float pw = (m2 - 2.0f * fc * m1 + fc * fc * m0) * (1.0f / 961.0f);
    float refined = logits[(size_t)r * C + c] - smooth * pw;

    if (last) {
        out[(size_t)r * C + c] = refined;
        return;
    }

    float mx = refined;
#pragma unroll
    for (int off = 16; off; off >>= 1) mx = fmaxf(mx, __shfl_xor(mx, off, 32));
    float e = expf(refined - mx);
    float s0 = e, s1 = e * fc, s2 = e * fc * fc;
#pragma unroll
    for (int off = 16; off; off >>= 1) {
        s0 += __shfl_xor(s0, off, 32);
        s1 += __shfl_xor(s1, off, 32);
        s2 += __shfl_xor(s2, off, 32);
    }
    if (c == 0) mu_out[r] = make_float2(s1 / s0, s2 / s0);
}

// ---------------------------------------------------------------------------
extern "C" void kernel_launch(void* const* d_in, const int* in_sizes, int n_in,
                              void* d_out, int out_size, void* d_ws, size_t ws_size,
                              hipStream_t stream) {
    const float* logits     = (const float*)d_in[0];
    const float* rois       = (const float*)d_in[1];
    const float* feats      = (const float*)d_in[2];
    const float* raw_sigma  = (const float*)d_in[3];
    const float* raw_smooth = (const float*)d_in[4];
    float* out = (float*)d_out;

    char* ws = (char*)d_ws;
    size_t off = 0;
    auto alloc = [&](size_t bytes) -> void* {
        void* p = ws + off;
        off += (bytes + 255) & ~(size_t)255;
        return p;
    };
    float4*   centers4 = (float4*)  alloc((size_t)ROWS * sizeof(float4));
    float*    invnorm  = (float*)   alloc((size_t)ROWS * 4);
    unsigned* adj      = (unsigned*)alloc((size_t)ROWS * NW * 4);
    uint2*    nbr      = (uint2*)   alloc((size_t)ROWS * CAP * 8);
    int*      nbr_cnt  = (int*)     alloc((size_t)ROWS * 4);
    float2*   mu_a     = (float2*)  alloc((size_t)ROWS * 8);
    float2*   mu_b     = (float2*)  alloc((size_t)ROWS * 8);

    pre_kernel<<<ROWS / 4, 256, 0, stream>>>(rois, feats, centers4, invnorm, (uint2*)adj);
    knn_kernel<<<ROWS / 16, 1024, 0, stream>>>(centers4, adj);
    build_kernel<<<ROWS, 512, 0, stream>>>(feats, centers4, invnorm, adj,
                                           nbr, nbr_cnt, raw_sigma, logits, mu_a);

    float2* mi = mu_a;
    float2* mo = mu_b;
    for (int it = 0; it < 5; ++it) {
        iter_kernel<<<ROWS / 8, 256, 0, stream>>>(logits, nbr, nbr_cnt,
                                                  mi, mo, out, raw_smooth,
                                                  (it == 4) ? 1 : 0);
        float2* tmp = mi; mi = mo; mo = tmp;
    }
}

// Round 12
// 80.220 us; speedup vs baseline: 1.2259x; 1.2259x over previous
//
#include <hip/hip_runtime.h>
#include <math.h>

// Problem constants (match reference setup_inputs)
constexpr int B = 2;
constexpr int N = 4096;
constexpr int C = 32;
constexpr int D = 256;
constexpr int K = 16;
constexpr int NW = N / 32;   // adjacency bitmask words per row = 128
constexpr int CAP = 128;     // max neighbors per row (16 out + in-degree)
constexpr int ROWS = B * N;  // 8192

// ---------------------------------------------------------------------------
// Kernel 1: per-row preprocess: centers(+sqnorm or INF if invalid), feature
// inv-norm. One wave (64 lanes) per row. Also zeroes the adjacency bitmask.
__global__ void pre_kernel(const float* __restrict__ rois,
                           const float* __restrict__ feats,
                           float4* __restrict__ centers4,
                           float* __restrict__ invnorm,
                           uint2* __restrict__ adj_zero) {
    const int t = threadIdx.x;
    const int wid = t >> 6, lane = t & 63;
    const int r = blockIdx.x * 4 + wid;

    // zero adjacency: 2048 blocks * 256 threads == ROWS*NW/2 uint2 elements
    adj_zero[blockIdx.x * 256 + t] = make_uint2(0u, 0u);

    if (r >= ROWS) return;

    const float4* f4 = reinterpret_cast<const float4*>(feats) + (size_t)r * (D / 4);
    float4 v = f4[lane];
    float ss = v.x * v.x + v.y * v.y + v.z * v.z + v.w * v.w;
#pragma unroll
    for (int off = 32; off; off >>= 1) ss += __shfl_xor(ss, off);

    if (lane == 0) {
        invnorm[r] = 1.0f / fmaxf(sqrtf(ss), 1e-6f);
        const float* rp = rois + (size_t)r * 6;
        float a0 = rp[0], a1 = rp[1], a2 = rp[2], a3 = rp[3], a4 = rp[4], a5 = rp[5];
        float cx = (a0 + a3) * 0.5f, cy = (a1 + a4) * 0.5f, cz = (a2 + a5) * 0.5f;
        float sq = cx * cx + cy * cy + cz * cz;
        float s = fabsf(a0) + fabsf(a1) + fabsf(a2) + fabsf(a3) + fabsf(a4) + fabsf(a5);
        centers4[r] = make_float4(cx, cy, cz, (s > 0.0f) ? sq : INFINITY);
    }
}

// ---------------------------------------------------------------------------
// Kernel 2: exact 16-NN, chunk-in-register structure (see R8 notes).
__global__ __launch_bounds__(1024, 8) void knn_kernel(const float4* __restrict__ centers4,
                                                      unsigned* __restrict__ adj) {
    __shared__ float4 s_c[N];                        // 64 KB
    __shared__ unsigned s_pm[16][64];                // 4 KB subset-min bits
    __shared__ unsigned long long s_buf[16][64];     // 8 KB survivor keys
    __shared__ int s_cnt[16];
    __shared__ float s_tau[16];

    const int t = threadIdx.x;
    const int lane = t & 63;
    const int wv = t >> 6;
    const int r0 = blockIdx.x * 16;        // first global row of block
    const int nbase = r0 & (N - 1);        // first in-batch row index
    const int gbase = r0 - nbase;          // batch offset (0 or N)

    if (t < 16) s_cnt[t] = 0;
    ((unsigned*)s_pm)[t] = 0x7F800000u;    // +INF bits (1024 entries exactly)
    for (int i = t; i < N; i += 1024) s_c[i] = centers4[gbase + i];
    __syncthreads();

    // wave-owned candidate chunk, kept in registers
    float4 cmv[4];
    int    mv[4];
#pragma unroll
    for (int u = 0; u < 4; ++u) {
        mv[u] = (wv << 8) + (u << 6) + lane;
        cmv[u] = s_c[mv[u]];
    }

    // ---- pass 1: per-row min over this lane's 4 candidates; merge via atomicMin ----
#pragma unroll 4
    for (int rr = 0; rr < 16; ++rr) {
        const int nrow = nbase + rr;
        const float4 rc = s_c[nrow];       // same-address broadcast, conflict-free
        float mn = INFINITY;
#pragma unroll
        for (int u = 0; u < 4; ++u) {
            float dist = fmaxf(rc.w + cmv[u].w -
                               2.0f * (rc.x * cmv[u].x + rc.y * cmv[u].y + rc.z * cmv[u].z), 0.0f);
            mn = fminf(mn, (mv[u] == nrow) ? INFINITY : dist);
        }
        atomicMin(&s_pm[rr][lane], __float_as_uint(mn));
    }
    __syncthreads();

    // ---- tau per row: wave rr sorts its row's 64 subset minima ----
    {
        float v = __uint_as_float(s_pm[wv][lane]);
#pragma unroll
        for (int k = 2; k <= 64; k <<= 1) {
#pragma unroll
            for (int j = k >> 1; j > 0; j >>= 1) {
                float o = __shfl_xor(v, j);
                bool take_min = (((lane & j) == 0) == ((lane & k) == 0));
                v = take_min ? fminf(v, o) : fmaxf(v, o);
            }
        }
        if (lane == 15) s_tau[wv] = v;     // 16th smallest
    }
    __syncthreads();

    // ---- pass 2: append survivors from the register chunk for all 16 rows ----
#pragma unroll 4
    for (int rr = 0; rr < 16; ++rr) {
        const int nrow = nbase + rr;
        const float tau = s_tau[rr];
        const float4 rc = s_c[nrow];
#pragma unroll
        for (int u = 0; u < 4; ++u) {
            float dist = fmaxf(rc.w + cmv[u].w -
                               2.0f * (rc.x * cmv[u].x + rc.y * cmv[u].y + rc.z * cmv[u].z), 0.0f);
            if (dist <= tau && mv[u] != nrow) {
                int pos = atomicAdd(&s_cnt[rr], 1);
                if (pos < 64)
                    s_buf[rr][pos] = ((unsigned long long)__float_as_uint(dist) << 32)
                                     | (unsigned)mv[u];
            }
        }
    }
    __syncthreads();

    // ---- selection: wave rr owns row rr ----
    const int rg = r0 + wv;                // global row
    const int n = nbase + wv;              // in-batch row
    const int cnt = s_cnt[wv];

    int my_sel = -1;
    if (cnt <= 64) {
        unsigned long long key = (lane < cnt) ? s_buf[wv][lane] : ~0ull;
#pragma unroll
        for (int k = 2; k <= 64; k <<= 1) {
#pragma unroll
            for (int j = k >> 1; j > 0; j >>= 1) {
                unsigned long long o = __shfl_xor(key, j);
                bool take_min = (((lane & j) == 0) == ((lane & k) == 0));
                unsigned long long mn = (key < o) ? key : o;
                unsigned long long mx = (key < o) ? o : key;
                key = take_min ? mn : mx;
            }
        }
        if (lane < K && key != ~0ull) my_sel = (int)(unsigned)key;
    } else {
        // exact fallback: 16 rounds of full rescan-argmin over LDS table
        const float4 cq = s_c[n];
        unsigned long long removed = 0ull;
        for (int round = 0; round < K; ++round) {
            float bd = INFINITY; int bi = 0x7FFFFFFF;
            for (int j = 0; j < 64; ++j) {
                const int m = lane + (j << 6);
                float4 cm = s_c[m];
                float dist = fmaxf(cq.w + cm.w -
                                   2.0f * (cq.x * cm.x + cq.y * cm.y + cq.z * cm.z), 0.0f);
                bool skip = ((removed >> j) & 1ull) || (m == n);
                if (!skip && dist < bd) { bd = dist; bi = m; }
            }
            float md = bd;
#pragma unroll
            for (int off = 32; off; off >>= 1) md = fminf(md, __shfl_xor(md, off));
            if (md == INFINITY) break;
            int kk = (bd == md) ? bi : 0x7FFFFFFF;
#pragma unroll
            for (int off = 32; off; off >>= 1) kk = min(kk, __shfl_xor(kk, off));
            if (lane == round) my_sel = kk;
            if (kk == bi) removed |= 1ull << (bi >> 6);
        }
    }

    if (my_sel >= 0) {
        atomicOr(&adj[(size_t)rg * NW + (my_sel >> 5)], 1u << (my_sel & 31));
        atomicOr(&adj[(size_t)(gbase + my_sel) * NW + (n >> 5)], 1u << (n & 31));
    }
}

// ---------------------------------------------------------------------------
// Kernel 3: build weighted neighbor lists. 256 threads (4 waves) per row.
// Weight phase uses 16-LANE GROUPS: each wave computes 4 neighbors at once
// (lane = 16*g + e; lane e of group g loads f4[e], f4[e+16], f4[e+32],
// f4[e+48] of neighbor i0+g — contiguous 256B segments per group), 4-step
// group reduce, broadcast cm/invnorm loads. Serial depth per wave ~2 for
// cnt<=32 (vs 8 with wave-per-neighbor). Fused: lanes <32 compute initial
// softmax moments mu0.
__global__ void build_kernel(const float* __restrict__ feats,
                             const float4* __restrict__ centers4,
                             const float* __restrict__ invnorm,
                             const unsigned* __restrict__ adj,
                             uint2* __restrict__ nbr,
                             int* __restrict__ nbr_cnt,
                             const float* __restrict__ raw_sigma,
                             const float* __restrict__ logits,
                             float2* __restrict__ mu0) {
    const int t = threadIdx.x;
    const int lane = t & 63;
    const int wv = t >> 6;          // 0..3
    const int r = blockIdx.x;
    const int base = r - (r & (N - 1));

    __shared__ int    s_off[NW];
    __shared__ int    s_wtot[2];
    __shared__ int    s_list[CAP];
    __shared__ float  s_w[CAP];
    __shared__ float4 s_fq[D / 4];
    __shared__ float  s_fsum[4];

    const float4* feats4 = reinterpret_cast<const float4*>(feats);
    if (t < D / 4) s_fq[t] = feats4[(size_t)r * (D / 4) + t];

    unsigned word = 0; int pc = 0;
    if (t < NW) {
        word = adj[(size_t)r * NW + t];
        pc = __popc(word);
    }
    int sc = pc;
#pragma unroll
    for (int off = 1; off < 64; off <<= 1) {
        int o = __shfl_up(sc, off);
        if (lane >= off) sc += o;
    }
    if (t < NW && lane == 63) s_wtot[wv] = sc;
    __syncthreads();
    const int total = s_wtot[0] + s_wtot[1];
    const int cnt = total > CAP ? CAP : total;
    if (t < NW) s_off[t] = sc - pc + ((wv == 1) ? s_wtot[0] : 0);
    __syncthreads();

    if (t < NW && word) {
        int o = s_off[t];
        unsigned w2 = word;
        while (w2) {
            int bit = __ffs(w2) - 1;
            if (o < CAP) s_list[o] = t * 32 + bit;
            ++o;
            w2 &= w2 - 1;
        }
    }
    __syncthreads();

    const float rs = raw_sigma[0];
    const float sigma = fmaxf(log1pf(expf(rs)), 1e-6f);
    const float nhalf_inv_s2 = -0.5f / (sigma * sigma);

    const float inq = invnorm[r];
    const float4 cq = centers4[r];

    // ---- weight phase: 16-lane groups, 4 neighbors per wave per step ----
    {
        const int g = lane >> 4;    // neighbor slot in wave (0..3)
        const int e = lane & 15;    // element slice (0..15)
        for (int i0 = wv * 4; i0 < cnt; i0 += 16) {
            const int i = i0 + g;
            const bool act = (i < cnt);
            const int gm = base + s_list[act ? i : 0];
            const size_t rowb = (size_t)gm * (D / 4);
            // 4 independent 16B loads per lane (group-contiguous 256B segments)
            float4 a0 = feats4[rowb + e];
            float4 a1 = feats4[rowb + e + 16];
            float4 a2 = feats4[rowb + e + 32];
            float4 a3 = feats4[rowb + e + 48];
            float4 cm = centers4[gm];   // broadcast within group
            float  inm = invnorm[gm];   // broadcast within group
            float4 q0 = s_fq[e], q1 = s_fq[e + 16], q2 = s_fq[e + 32], q3 = s_fq[e + 48];
            float p = a0.x * q0.x + a0.y * q0.y + a0.z * q0.z + a0.w * q0.w
                    + a1.x * q1.x + a1.y * q1.y + a1.z * q1.z + a1.w * q1.w
                    + a2.x * q2.x + a2.y * q2.y + a2.z * q2.z + a2.w * q2.w
                    + a3.x * q3.x + a3.y * q3.y + a3.z * q3.z + a3.w * q3.w;
#pragma unroll
            for (int off = 1; off < 16; off <<= 1) p += __shfl_xor(p, off);
            float cosv = p * inq * inm;
            float aff = fminf(fmaxf((cosv + 1.0f) * 0.5f, 0.0f), 1.0f);
            float dist = fmaxf(cq.w + cm.w -
                               2.0f * (cq.x * cm.x + cq.y * cm.y + cq.z * cm.z), 0.0f);
            if (e == 0 && act) s_w[i] = expf(dist * nhalf_inv_s2) * aff;
        }
    }
    __syncthreads();

    // wave-parallel weight sum (deterministic)
    float ps = 0.0f;
    for (int i = t; i < cnt; i += 256) ps += s_w[i];
#pragma unroll
    for (int off = 32; off; off >>= 1) ps += __shfl_xor(ps, off);
    if (lane == 0) s_fsum[wv] = ps;
    __syncthreads();
    const float inv_sum = 1.0f / fmaxf(s_fsum[0] + s_fsum[1] + s_fsum[2] + s_fsum[3], 1e-6f);

    for (int i = t; i < cnt; i += 256) {
        nbr[(size_t)r * CAP + i] = make_uint2((unsigned)s_list[i],
                                              __float_as_uint(s_w[i] * inv_sum));
    }
    if (t == 0) nbr_cnt[r] = cnt;

    // fused initial softmax moments for this row (lanes 0..31)
    if (t < C) {
        float x = logits[(size_t)r * C + t];
        float mx = x;
#pragma unroll
        for (int off = 16; off; off >>= 1) mx = fmaxf(mx, __shfl_xor(mx, off, 32));
        float e = expf(x - mx);
        const float fc = (float)t;
        float s0 = e, s1 = e * fc, s2 = e * fc * fc;
#pragma unroll
        for (int off = 16; off; off >>= 1) {
            s0 += __shfl_xor(s0, off, 32);
            s1 += __shfl_xor(s1, off, 32);
            s2 += __shfl_xor(s2, off, 32);
        }
        if (t == 0) mu0[r] = make_float2(s1 / s0, s2 / s0);
    }
}

// ---------------------------------------------------------------------------
// Kernel 4: one mean-field iteration, MOMENT-COMPRESSED (see R9 notes).
__global__ void iter_kernel(const float* __restrict__ logits,
                            const uint2* __restrict__ nbr,
                            const int* __restrict__ nbr_cnt,
                            const float2* __restrict__ mu_in,
                            float2* __restrict__ mu_out,
                            float* __restrict__ out,
                            const float* __restrict__ raw_smooth,
                            int last) {
    const int t = threadIdx.x;
    const int r = blockIdx.x * 8 + (t >> 5);
    const int c = t & 31;
    const int base = r - (r & (N - 1));
    const float smooth = log1pf(expf(raw_smooth[0]));

    const int cnt = nbr_cnt[r];
    const uint2* np = nbr + (size_t)r * CAP;

    float m0 = 0.0f, m1 = 0.0f, m2 = 0.0f;
    for (int j = c; j < cnt; j += 32) {
        uint2 e = np[j];
        float w = __uint_as_float(e.y);
        float2 mu = mu_in[base + (int)e.x];
        m0 += w;
        m1 += w * mu.x;
        m2 += w * mu.y;
    }
#pragma unroll
    for (int off = 16; off; off >>= 1) {
        m0 += __shfl_xor(m0, off, 32);
        m1 += __shfl_xor(m1, off, 32);
        m2 += __shfl_xor(m2, off, 32);
    }

    const float fc = (float)c;
    float pw = (m2 - 2.0f * fc * m1 + fc * fc * m0) * (1.0f / 961.0f);
    float refined = logits[(size_t)r * C + c] - smooth * pw;

    if (last) {
        out[(size_t)r * C + c] = refined;
        return;
    }

    float mx = refined;
#pragma unroll
    for (int off = 16; off; off >>= 1) mx = fmaxf(mx, __shfl_xor(mx, off, 32));
    float e = expf(refined - mx);
    float s0 = e, s1 = e * fc, s2 = e * fc * fc;
#pragma unroll
    for (int off = 16; off; off >>= 1) {
        s0 += __shfl_xor(s0, off, 32);
        s1 += __shfl_xor(s1, off, 32);
        s2 += __shfl_xor(s2, off, 32);
    }
    if (c == 0) mu_out[r] = make_float2(s1 / s0, s2 / s0);
}

// ---------------------------------------------------------------------------
extern "C" void kernel_launch(void* const* d_in, const int* in_sizes, int n_in,
                              void* d_out, int out_size, void* d_ws, size_t ws_size,
                              hipStream_t stream) {
    const float* logits     = (const float*)d_in[0];
    const float* rois       = (const float*)d_in[1];
    const float* feats      = (const float*)d_in[2];
    const float* raw_sigma  = (const float*)d_in[3];
    const float* raw_smooth = (const float*)d_in[4];
    float* out = (float*)d_out;

    char* ws = (char*)d_ws;
    size_t off = 0;
    auto alloc = [&](size_t bytes) -> void* {
        void* p = ws + off;
        off += (bytes + 255) & ~(size_t)255;
        return p;
    };
    float4*   centers4 = (float4*)  alloc((size_t)ROWS * sizeof(float4));
    float*    invnorm  = (float*)   alloc((size_t)ROWS * 4);
    unsigned* adj      = (unsigned*)alloc((size_t)ROWS * NW * 4);
    uint2*    nbr      = (uint2*)   alloc((size_t)ROWS * CAP * 8);
    int*      nbr_cnt  = (int*)     alloc((size_t)ROWS * 4);
    float2*   mu_a     = (float2*)  alloc((size_t)ROWS * 8);
    float2*   mu_b     = (float2*)  alloc((size_t)ROWS * 8);

    pre_kernel<<<ROWS / 4, 256, 0, stream>>>(rois, feats, centers4, invnorm, (uint2*)adj);
    knn_kernel<<<ROWS / 16, 1024, 0, stream>>>(centers4, adj);
    build_kernel<<<ROWS, 256, 0, stream>>>(feats, centers4, invnorm, adj,
                                           nbr, nbr_cnt, raw_sigma, logits, mu_a);

    float2* mi = mu_a;
    float2* mo = mu_b;
    for (int it = 0; it < 5; ++it) {
        iter_kernel<<<ROWS / 8, 256, 0, stream>>>(logits, nbr, nbr_cnt,
                                                  mi, mo, out, raw_smooth,
                                                  (it == 4) ? 1 : 0);
        float2* tmp = mi; mi = mo; mo = tmp;
    }
}

// Round 13
// 80.062 us; speedup vs baseline: 1.2284x; 1.0020x over previous
//
#include <hip/hip_runtime.h>
#include <math.h>

// Problem constants (match reference setup_inputs)
constexpr int B = 2;
constexpr int N = 4096;
constexpr int C = 32;
constexpr int D = 256;
constexpr int K = 16;
constexpr int NW = N / 32;   // adjacency bitmask words per row = 128
constexpr int CAP = 128;     // max neighbors per row (16 out + in-degree)
constexpr int ROWS = B * N;  // 8192

__device__ __forceinline__ unsigned short f2bf(float f) {   // RNE f32 -> bf16
    unsigned u = __float_as_uint(f);
    return (unsigned short)((u + 0x7fffu + ((u >> 16) & 1u)) >> 16);
}
__device__ __forceinline__ float bflo(unsigned u) { return __uint_as_float(u << 16); }
__device__ __forceinline__ float bfhi(unsigned u) { return __uint_as_float(u & 0xffff0000u); }

// ---------------------------------------------------------------------------
// Kernel 1: per-row preprocess: centers(+sqnorm or INF if invalid), and a
// PRE-NORMALIZED bf16 copy of the feature row (feats/max(|f|,1e-6), RNE).
// One wave per row; also zeroes the adjacency bitmask.
__global__ void pre_kernel(const float* __restrict__ rois,
                           const float* __restrict__ feats,
                           float4* __restrict__ centers4,
                           unsigned short* __restrict__ fnbf,
                           uint2* __restrict__ adj_zero) {
    const int t = threadIdx.x;
    const int wid = t >> 6, lane = t & 63;
    const int r = blockIdx.x * 4 + wid;

    // zero adjacency: 2048 blocks * 256 threads == ROWS*NW/2 uint2 elements
    adj_zero[blockIdx.x * 256 + t] = make_uint2(0u, 0u);

    if (r >= ROWS) return;

    const float4* f4 = reinterpret_cast<const float4*>(feats) + (size_t)r * (D / 4);
    float4 v = f4[lane];
    float ss = v.x * v.x + v.y * v.y + v.z * v.z + v.w * v.w;
#pragma unroll
    for (int off = 32; off; off >>= 1) ss += __shfl_xor(ss, off);

    const float invn = 1.0f / fmaxf(sqrtf(ss), 1e-6f);
    unsigned u0 = (unsigned)f2bf(v.x * invn) | ((unsigned)f2bf(v.y * invn) << 16);
    unsigned u1 = (unsigned)f2bf(v.z * invn) | ((unsigned)f2bf(v.w * invn) << 16);
    *reinterpret_cast<uint2*>(fnbf + (size_t)r * D + lane * 4) = make_uint2(u0, u1);

    if (lane == 0) {
        const float* rp = rois + (size_t)r * 6;
        float a0 = rp[0], a1 = rp[1], a2 = rp[2], a3 = rp[3], a4 = rp[4], a5 = rp[5];
        float cx = (a0 + a3) * 0.5f, cy = (a1 + a4) * 0.5f, cz = (a2 + a5) * 0.5f;
        float sq = cx * cx + cy * cy + cz * cz;
        float s = fabsf(a0) + fabsf(a1) + fabsf(a2) + fabsf(a3) + fabsf(a4) + fabsf(a5);
        centers4[r] = make_float4(cx, cy, cz, (s > 0.0f) ? sq : INFINITY);
    }
}

// ---------------------------------------------------------------------------
// Kernel 2: exact 16-NN, chunk-in-register structure (see R8 notes).
__global__ __launch_bounds__(1024, 8) void knn_kernel(const float4* __restrict__ centers4,
                                                      unsigned* __restrict__ adj) {
    __shared__ float4 s_c[N];                        // 64 KB
    __shared__ unsigned s_pm[16][64];                // 4 KB subset-min bits
    __shared__ unsigned long long s_buf[16][64];     // 8 KB survivor keys
    __shared__ int s_cnt[16];
    __shared__ float s_tau[16];

    const int t = threadIdx.x;
    const int lane = t & 63;
    const int wv = t >> 6;
    const int r0 = blockIdx.x * 16;        // first global row of block
    const int nbase = r0 & (N - 1);        // first in-batch row index
    const int gbase = r0 - nbase;          // batch offset (0 or N)

    if (t < 16) s_cnt[t] = 0;
    ((unsigned*)s_pm)[t] = 0x7F800000u;    // +INF bits (1024 entries exactly)
    for (int i = t; i < N; i += 1024) s_c[i] = centers4[gbase + i];
    __syncthreads();

    // wave-owned candidate chunk, kept in registers
    float4 cmv[4];
    int    mv[4];
#pragma unroll
    for (int u = 0; u < 4; ++u) {
        mv[u] = (wv << 8) + (u << 6) + lane;
        cmv[u] = s_c[mv[u]];
    }

    // ---- pass 1: per-row min over this lane's 4 candidates; merge via atomicMin ----
#pragma unroll 4
    for (int rr = 0; rr < 16; ++rr) {
        const int nrow = nbase + rr;
        const float4 rc = s_c[nrow];       // same-address broadcast, conflict-free
        float mn = INFINITY;
#pragma unroll
        for (int u = 0; u < 4; ++u) {
            float dist = fmaxf(rc.w + cmv[u].w -
                               2.0f * (rc.x * cmv[u].x + rc.y * cmv[u].y + rc.z * cmv[u].z), 0.0f);
            mn = fminf(mn, (mv[u] == nrow) ? INFINITY : dist);
        }
        atomicMin(&s_pm[rr][lane], __float_as_uint(mn));
    }
    __syncthreads();

    // ---- tau per row: wave rr sorts its row's 64 subset minima ----
    {
        float v = __uint_as_float(s_pm[wv][lane]);
#pragma unroll
        for (int k = 2; k <= 64; k <<= 1) {
#pragma unroll
            for (int j = k >> 1; j > 0; j >>= 1) {
                float o = __shfl_xor(v, j);
                bool take_min = (((lane & j) == 0) == ((lane & k) == 0));
                v = take_min ? fminf(v, o) : fmaxf(v, o);
            }
        }
        if (lane == 15) s_tau[wv] = v;     // 16th smallest
    }
    __syncthreads();

    // ---- pass 2: append survivors from the register chunk for all 16 rows ----
#pragma unroll 4
    for (int rr = 0; rr < 16; ++rr) {
        const int nrow = nbase + rr;
        const float tau = s_tau[rr];
        const float4 rc = s_c[nrow];
#pragma unroll
        for (int u = 0; u < 4; ++u) {
            float dist = fmaxf(rc.w + cmv[u].w -
                               2.0f * (rc.x * cmv[u].x + rc.y * cmv[u].y + rc.z * cmv[u].z), 0.0f);
            if (dist <= tau && mv[u] != nrow) {
                int pos = atomicAdd(&s_cnt[rr], 1);
                if (pos < 64)
                    s_buf[rr][pos] = ((unsigned long long)__float_as_uint(dist) << 32)
                                     | (unsigned)mv[u];
            }
        }
    }
    __syncthreads();

    // ---- selection: wave rr owns row rr ----
    const int rg = r0 + wv;                // global row
    const int n = nbase + wv;              // in-batch row
    const int cnt = s_cnt[wv];

    int my_sel = -1;
    if (cnt <= 64) {
        unsigned long long key = (lane < cnt) ? s_buf[wv][lane] : ~0ull;
#pragma unroll
        for (int k = 2; k <= 64; k <<= 1) {
#pragma unroll
            for (int j = k >> 1; j > 0; j >>= 1) {
                unsigned long long o = __shfl_xor(key, j);
                bool take_min = (((lane & j) == 0) == ((lane & k) == 0));
                unsigned long long mn = (key < o) ? key : o;
                unsigned long long mx = (key < o) ? o : key;
                key = take_min ? mn : mx;
            }
        }
        if (lane < K && key != ~0ull) my_sel = (int)(unsigned)key;
    } else {
        // exact fallback: 16 rounds of full rescan-argmin over LDS table
        const float4 cq = s_c[n];
        unsigned long long removed = 0ull;
        for (int round = 0; round < K; ++round) {
            float bd = INFINITY; int bi = 0x7FFFFFFF;
            for (int j = 0; j < 64; ++j) {
                const int m = lane + (j << 6);
                float4 cm = s_c[m];
                float dist = fmaxf(cq.w + cm.w -
                                   2.0f * (cq.x * cm.x + cq.y * cm.y + cq.z * cm.z), 0.0f);
                bool skip = ((removed >> j) & 1ull) || (m == n);
                if (!skip && dist < bd) { bd = dist; bi = m; }
            }
            float md = bd;
#pragma unroll
            for (int off = 32; off; off >>= 1) md = fminf(md, __shfl_xor(md, off));
            if (md == INFINITY) break;
            int kk = (bd == md) ? bi : 0x7FFFFFFF;
#pragma unroll
            for (int off = 32; off; off >>= 1) kk = min(kk, __shfl_xor(kk, off));
            if (lane == round) my_sel = kk;
            if (kk == bi) removed |= 1ull << (bi >> 6);
        }
    }

    if (my_sel >= 0) {
        atomicOr(&adj[(size_t)rg * NW + (my_sel >> 5)], 1u << (my_sel & 31));
        atomicOr(&adj[(size_t)(gbase + my_sel) * NW + (n >> 5)], 1u << (n & 31));
    }
}

// ---------------------------------------------------------------------------
// Kernel 3: build weighted neighbor lists. 256 threads (4 waves) per row.
// Cosine uses PRE-NORMALIZED BF16 features (half the gather bytes, no invnorm
// loads). 16-lane groups: 4 neighbors per wave concurrently; lane e of a
// group loads 2 uint4 (16 bf16 each) of the neighbor row; q row staged once
// in LDS as f32 in a group-matched layout (s_fqx[s][e], 2-way banks max).
// Fused: lanes <32 compute initial softmax moments mu0.
__global__ void build_kernel(const unsigned short* __restrict__ fnbf,
                             const float4* __restrict__ centers4,
                             const unsigned* __restrict__ adj,
                             uint2* __restrict__ nbr,
                             int* __restrict__ nbr_cnt,
                             const float* __restrict__ raw_sigma,
                             const float* __restrict__ logits,
                             float2* __restrict__ mu0) {
    const int t = threadIdx.x;
    const int lane = t & 63;
    const int wv = t >> 6;          // 0..3
    const int r = blockIdx.x;
    const int base = r - (r & (N - 1));

    __shared__ int    s_off[NW];
    __shared__ int    s_wtot[2];
    __shared__ int    s_list[CAP];
    __shared__ float  s_w[CAP];
    __shared__ float4 s_fqx[4][16];   // q row, f32, group-matched layout
    __shared__ float  s_fsum[4];

    const uint4* fn4 = reinterpret_cast<const uint4*>(fnbf);

    // stage q row: thread t<64 fills s_fqx[s][e] = q[(s>>1)*128 + 8e + (s&1)*4 .. +4)
    if (t < 64) {
        const int s = t >> 4, e = t & 15;
        const int off = ((s >> 1) << 7) + (e << 3) + ((s & 1) << 2);
        uint2 w = *reinterpret_cast<const uint2*>(fnbf + (size_t)r * D + off);
        s_fqx[s][e] = make_float4(bflo(w.x), bfhi(w.x), bflo(w.y), bfhi(w.y));
    }

    unsigned word = 0; int pc = 0;
    if (t < NW) {
        word = adj[(size_t)r * NW + t];
        pc = __popc(word);
    }
    int sc = pc;
#pragma unroll
    for (int off = 1; off < 64; off <<= 1) {
        int o = __shfl_up(sc, off);
        if (lane >= off) sc += o;
    }
    if (t < NW && lane == 63) s_wtot[wv] = sc;
    __syncthreads();
    const int total = s_wtot[0] + s_wtot[1];
    const int cnt = total > CAP ? CAP : total;
    if (t < NW) s_off[t] = sc - pc + ((wv == 1) ? s_wtot[0] : 0);
    __syncthreads();

    if (t < NW && word) {
        int o = s_off[t];
        unsigned w2 = word;
        while (w2) {
            int bit = __ffs(w2) - 1;
            if (o < CAP) s_list[o] = t * 32 + bit;
            ++o;
            w2 &= w2 - 1;
        }
    }
    __syncthreads();

    const float rs = raw_sigma[0];
    const float sigma = fmaxf(log1pf(expf(rs)), 1e-6f);
    const float nhalf_inv_s2 = -0.5f / (sigma * sigma);

    const float4 cq = centers4[r];

    // ---- weight phase: 16-lane groups, 4 neighbors per wave per step ----
    {
        const int g = lane >> 4;    // neighbor slot in wave (0..3)
        const int e = lane & 15;    // element slice (0..15)
        for (int i0 = wv * 4; i0 < cnt; i0 += 16) {
            const int i = i0 + g;
            const bool act = (i < cnt);
            const int gm = base + s_list[act ? i : 0];
            const size_t rowb = (size_t)gm * (D / 16);   // uint4 units (16 per row)
            uint4 a = fn4[rowb + (e >> 1)];              // wait — see layout below
            // row = 256 bf16 = 32 uint4; lane e covers elements [8e,8e+8) and [128+8e,128+8e+8)
            a = fn4[(size_t)gm * 32 + e];
            uint4 b = fn4[(size_t)gm * 32 + 16 + e];
            float4 cm = centers4[gm];   // broadcast within group
            float4 qa0 = s_fqx[0][e], qa1 = s_fqx[1][e];
            float4 qb0 = s_fqx[2][e], qb1 = s_fqx[3][e];
            float p = bflo(a.x) * qa0.x + bfhi(a.x) * qa0.y
                    + bflo(a.y) * qa0.z + bfhi(a.y) * qa0.w
                    + bflo(a.z) * qa1.x + bfhi(a.z) * qa1.y
                    + bflo(a.w) * qa1.z + bfhi(a.w) * qa1.w
                    + bflo(b.x) * qb0.x + bfhi(b.x) * qb0.y
                    + bflo(b.y) * qb0.z + bfhi(b.y) * qb0.w
                    + bflo(b.z) * qb1.x + bfhi(b.z) * qb1.y
                    + bflo(b.w) * qb1.z + bfhi(b.w) * qb1.w;
#pragma unroll
            for (int off = 1; off < 16; off <<= 1) p += __shfl_xor(p, off);
            float aff = fminf(fmaxf((p + 1.0f) * 0.5f, 0.0f), 1.0f);
            float dist = fmaxf(cq.w + cm.w -
                               2.0f * (cq.x * cm.x + cq.y * cm.y + cq.z * cm.z), 0.0f);
            if (e == 0 && act) s_w[i] = expf(dist * nhalf_inv_s2) * aff;
        }
    }
    __syncthreads();

    // wave-parallel weight sum (deterministic)
    float ps = 0.0f;
    for (int i = t; i < cnt; i += 256) ps += s_w[i];
#pragma unroll
    for (int off = 32; off; off >>= 1) ps += __shfl_xor(ps, off);
    if (lane == 0) s_fsum[wv] = ps;
    __syncthreads();
    const float inv_sum = 1.0f / fmaxf(s_fsum[0] + s_fsum[1] + s_fsum[2] + s_fsum[3], 1e-6f);

    for (int i = t; i < cnt; i += 256) {
        nbr[(size_t)r * CAP + i] = make_uint2((unsigned)s_list[i],
                                              __float_as_uint(s_w[i] * inv_sum));
    }
    if (t == 0) nbr_cnt[r] = cnt;

    // fused initial softmax moments for this row (lanes 0..31)
    if (t < C) {
        float x = logits[(size_t)r * C + t];
        float mx = x;
#pragma unroll
        for (int off = 16; off; off >>= 1) mx = fmaxf(mx, __shfl_xor(mx, off, 32));
        float e = expf(x - mx);
        const float fc = (float)t;
        float s0 = e, s1 = e * fc, s2 = e * fc * fc;
#pragma unroll
        for (int off = 16; off; off >>= 1) {
            s0 += __shfl_xor(s0, off, 32);
            s1 += __shfl_xor(s1, off, 32);
            s2 += __shfl_xor(s2, off, 32);
        }
        if (t == 0) mu0[r] = make_float2(s1 / s0, s2 / s0);
    }
}

// ---------------------------------------------------------------------------
// Kernel 4: one mean-field iteration, MOMENT-COMPRESSED (see R9 notes).
__global__ void iter_kernel(const float* __restrict__ logits,
                            const uint2* __restrict__ nbr,
                            const int* __restrict__ nbr_cnt,
                            const float2* __restrict__ mu_in,
                            float2* __restrict__ mu_out,
                            float* __restrict__ out,
                            const float* __restrict__ raw_smooth,
                            int last) {
    const int t = threadIdx.x;
    const int r = blockIdx.x * 8 + (t >> 5);
    const int c = t & 31;
    const int base = r - (r & (N - 1));
    const float smooth = log1pf(expf(raw_smooth[0]));

    const int cnt = nbr_cnt[r];
    const uint2* np = nbr + (size_t)r * CAP;

    float m0 = 0.0f, m1 = 0.0f, m2 = 0.0f;
    for (int j = c; j < cnt; j += 32) {
        uint2 e = np[j];
        float w = __uint_as_float(e.y);
        float2 mu = mu_in[base + (int)e.x];
        m0 += w;
        m1 += w * mu.x;
        m2 += w * mu.y;
    }
#pragma unroll
    for (int off = 16; off; off >>= 1) {
        m0 += __shfl_xor(m0, off, 32);
        m1 += __shfl_xor(m1, off, 32);
        m2 += __shfl_xor(m2, off, 32);
    }

    const float fc = (float)c;
    float pw = (m2 - 2.0f * fc * m1 + fc * fc * m0) * (1.0f / 961.0f);
    float refined = logits[(size_t)r * C + c] - smooth * pw;

    if (last) {
        out[(size_t)r * C + c] = refined;
        return;
    }

    float mx = refined;
#pragma unroll
    for (int off = 16; off; off >>= 1) mx = fmaxf(mx, __shfl_xor(mx, off, 32));
    float e = expf(refined - mx);
    float s0 = e, s1 = e * fc, s2 = e * fc * fc;
#pragma unroll
    for (int off = 16; off; off >>= 1) {
        s0 += __shfl_xor(s0, off, 32);
        s1 += __shfl_xor(s1, off, 32);
        s2 += __shfl_xor(s2, off, 32);
    }
    if (c == 0) mu_out[r] = make_float2(s1 / s0, s2 / s0);
}

// ---------------------------------------------------------------------------
extern "C" void kernel_launch(void* const* d_in, const int* in_sizes, int n_in,
                              void* d_out, int out_size, void* d_ws, size_t ws_size,
                              hipStream_t stream) {
    const float* logits     = (const float*)d_in[0];
    const float* rois       = (const float*)d_in[1];
    const float* feats      = (const float*)d_in[2];
    const float* raw_sigma  = (const float*)d_in[3];
    const float* raw_smooth = (const float*)d_in[4];
    float* out = (float*)d_out;

    char* ws = (char*)d_ws;
    size_t off = 0;
    auto alloc = [&](size_t bytes) -> void* {
        void* p = ws + off;
        off += (bytes + 255) & ~(size_t)255;
        return p;
    };
    float4*         centers4 = (float4*)        alloc((size_t)ROWS * sizeof(float4));
    unsigned short* fnbf     = (unsigned short*)alloc((size_t)ROWS * D * 2);
    unsigned*       adj      = (unsigned*)      alloc((size_t)ROWS * NW * 4);
    uint2*          nbr      = (uint2*)         alloc((size_t)ROWS * CAP * 8);
    int*            nbr_cnt  = (int*)           alloc((size_t)ROWS * 4);
    float2*         mu_a     = (float2*)        alloc((size_t)ROWS * 8);
    float2*         mu_b     = (float2*)        alloc((size_t)ROWS * 8);

    pre_kernel<<<ROWS / 4, 256, 0, stream>>>(rois, feats, centers4, fnbf, (uint2*)adj);
    knn_kernel<<<ROWS / 16, 1024, 0, stream>>>(centers4, adj);
    build_kernel<<<ROWS, 256, 0, stream>>>(fnbf, centers4, adj,
                                           nbr, nbr_cnt, raw_sigma, logits, mu_a);

    float2* mi = mu_a;
    float2* mo = mu_b;
    for (int it = 0; it < 5; ++it) {
        iter_kernel<<<ROWS / 8, 256, 0, stream>>>(logits, nbr, nbr_cnt,
                                                  mi, mo, out, raw_smooth,
                                                  (it == 4) ? 1 : 0);
        float2* tmp = mi; mi = mo; mo = tmp;
    }
}

// Round 14
// 71.423 us; speedup vs baseline: 1.3769x; 1.1209x over previous
//
#include <hip/hip_runtime.h>
#include <math.h>

// Problem constants (match reference setup_inputs)
constexpr int B = 2;
constexpr int N = 4096;
constexpr int C = 32;
constexpr int D = 256;
constexpr int K = 16;
constexpr int NW = N / 32;   // adjacency bitmask words per row = 128
constexpr int CAP = 128;     // max neighbors per row (16 out + in-degree)
constexpr int ROWS = B * N;  // 8192

__device__ __forceinline__ unsigned short f2bf(float f) {   // RNE f32 -> bf16
    unsigned u = __float_as_uint(f);
    return (unsigned short)((u + 0x7fffu + ((u >> 16) & 1u)) >> 16);
}
__device__ __forceinline__ float bflo(unsigned u) { return __uint_as_float(u << 16); }
__device__ __forceinline__ float bfhi(unsigned u) { return __uint_as_float(u & 0xffff0000u); }

// ---------------------------------------------------------------------------
// Kernel 1: per-row preprocess: centers(+sqnorm or INF if invalid), and a
// PRE-NORMALIZED bf16 copy of the feature row. One wave per row; also zeroes
// the adjacency bitmask.
__global__ void pre_kernel(const float* __restrict__ rois,
                           const float* __restrict__ feats,
                           float4* __restrict__ centers4,
                           unsigned short* __restrict__ fnbf,
                           uint2* __restrict__ adj_zero) {
    const int t = threadIdx.x;
    const int wid = t >> 6, lane = t & 63;
    const int r = blockIdx.x * 4 + wid;

    // zero adjacency: 2048 blocks * 256 threads == ROWS*NW/2 uint2 elements
    adj_zero[blockIdx.x * 256 + t] = make_uint2(0u, 0u);

    if (r >= ROWS) return;

    const float4* f4 = reinterpret_cast<const float4*>(feats) + (size_t)r * (D / 4);
    float4 v = f4[lane];
    float ss = v.x * v.x + v.y * v.y + v.z * v.z + v.w * v.w;
#pragma unroll
    for (int off = 32; off; off >>= 1) ss += __shfl_xor(ss, off);

    const float invn = 1.0f / fmaxf(sqrtf(ss), 1e-6f);
    unsigned u0 = (unsigned)f2bf(v.x * invn) | ((unsigned)f2bf(v.y * invn) << 16);
    unsigned u1 = (unsigned)f2bf(v.z * invn) | ((unsigned)f2bf(v.w * invn) << 16);
    *reinterpret_cast<uint2*>(fnbf + (size_t)r * D + lane * 4) = make_uint2(u0, u1);

    if (lane == 0) {
        const float* rp = rois + (size_t)r * 6;
        float a0 = rp[0], a1 = rp[1], a2 = rp[2], a3 = rp[3], a4 = rp[4], a5 = rp[5];
        float cx = (a0 + a3) * 0.5f, cy = (a1 + a4) * 0.5f, cz = (a2 + a5) * 0.5f;
        float sq = cx * cx + cy * cy + cz * cz;
        float s = fabsf(a0) + fabsf(a1) + fabsf(a2) + fabsf(a3) + fabsf(a4) + fabsf(a5);
        centers4[r] = make_float4(cx, cy, cz, (s > 0.0f) ? sq : INFINITY);
    }
}

// ---------------------------------------------------------------------------
// Kernel 2: exact 16-NN, chunk-in-register structure (see R8 notes).
__global__ __launch_bounds__(1024, 8) void knn_kernel(const float4* __restrict__ centers4,
                                                      unsigned* __restrict__ adj) {
    __shared__ float4 s_c[N];                        // 64 KB
    __shared__ unsigned s_pm[16][64];                // 4 KB subset-min bits
    __shared__ unsigned long long s_buf[16][64];     // 8 KB survivor keys
    __shared__ int s_cnt[16];
    __shared__ float s_tau[16];

    const int t = threadIdx.x;
    const int lane = t & 63;
    const int wv = t >> 6;
    const int r0 = blockIdx.x * 16;        // first global row of block
    const int nbase = r0 & (N - 1);        // first in-batch row index
    const int gbase = r0 - nbase;          // batch offset (0 or N)

    if (t < 16) s_cnt[t] = 0;
    ((unsigned*)s_pm)[t] = 0x7F800000u;    // +INF bits (1024 entries exactly)
    for (int i = t; i < N; i += 1024) s_c[i] = centers4[gbase + i];
    __syncthreads();

    // wave-owned candidate chunk, kept in registers
    float4 cmv[4];
    int    mv[4];
#pragma unroll
    for (int u = 0; u < 4; ++u) {
        mv[u] = (wv << 8) + (u << 6) + lane;
        cmv[u] = s_c[mv[u]];
    }

    // ---- pass 1: per-row min over this lane's 4 candidates; merge via atomicMin ----
#pragma unroll 4
    for (int rr = 0; rr < 16; ++rr) {
        const int nrow = nbase + rr;
        const float4 rc = s_c[nrow];       // same-address broadcast, conflict-free
        float mn = INFINITY;
#pragma unroll
        for (int u = 0; u < 4; ++u) {
            float dist = fmaxf(rc.w + cmv[u].w -
                               2.0f * (rc.x * cmv[u].x + rc.y * cmv[u].y + rc.z * cmv[u].z), 0.0f);
            mn = fminf(mn, (mv[u] == nrow) ? INFINITY : dist);
        }
        atomicMin(&s_pm[rr][lane], __float_as_uint(mn));
    }
    __syncthreads();

    // ---- tau per row: wave rr sorts its row's 64 subset minima ----
    {
        float v = __uint_as_float(s_pm[wv][lane]);
#pragma unroll
        for (int k = 2; k <= 64; k <<= 1) {
#pragma unroll
            for (int j = k >> 1; j > 0; j >>= 1) {
                float o = __shfl_xor(v, j);
                bool take_min = (((lane & j) == 0) == ((lane & k) == 0));
                v = take_min ? fminf(v, o) : fmaxf(v, o);
            }
        }
        if (lane == 15) s_tau[wv] = v;     // 16th smallest
    }
    __syncthreads();

    // ---- pass 2: append survivors from the register chunk for all 16 rows ----
#pragma unroll 4
    for (int rr = 0; rr < 16; ++rr) {
        const int nrow = nbase + rr;
        const float tau = s_tau[rr];
        const float4 rc = s_c[nrow];
#pragma unroll
        for (int u = 0; u < 4; ++u) {
            float dist = fmaxf(rc.w + cmv[u].w -
                               2.0f * (rc.x * cmv[u].x + rc.y * cmv[u].y + rc.z * cmv[u].z), 0.0f);
            if (dist <= tau && mv[u] != nrow) {
                int pos = atomicAdd(&s_cnt[rr], 1);
                if (pos < 64)
                    s_buf[rr][pos] = ((unsigned long long)__float_as_uint(dist) << 32)
                                     | (unsigned)mv[u];
            }
        }
    }
    __syncthreads();

    // ---- selection: wave rr owns row rr ----
    const int rg = r0 + wv;                // global row
    const int n = nbase + wv;              // in-batch row
    const int cnt = s_cnt[wv];

    int my_sel = -1;
    if (cnt <= 64) {
        unsigned long long key = (lane < cnt) ? s_buf[wv][lane] : ~0ull;
#pragma unroll
        for (int k = 2; k <= 64; k <<= 1) {
#pragma unroll
            for (int j = k >> 1; j > 0; j >>= 1) {
                unsigned long long o = __shfl_xor(key, j);
                bool take_min = (((lane & j) == 0) == ((lane & k) == 0));
                unsigned long long mn = (key < o) ? key : o;
                unsigned long long mx = (key < o) ? o : key;
                key = take_min ? mn : mx;
            }
        }
        if (lane < K && key != ~0ull) my_sel = (int)(unsigned)key;
    } else {
        // exact fallback: 16 rounds of full rescan-argmin over LDS table
        const float4 cq = s_c[n];
        unsigned long long removed = 0ull;
        for (int round = 0; round < K; ++round) {
            float bd = INFINITY; int bi = 0x7FFFFFFF;
            for (int j = 0; j < 64; ++j) {
                const int m = lane + (j << 6);
                float4 cm = s_c[m];
                float dist = fmaxf(cq.w + cm.w -
                                   2.0f * (cq.x * cm.x + cq.y * cm.y + cq.z * cm.z), 0.0f);
                bool skip = ((removed >> j) & 1ull) || (m == n);
                if (!skip && dist < bd) { bd = dist; bi = m; }
            }
            float md = bd;
#pragma unroll
            for (int off = 32; off; off >>= 1) md = fminf(md, __shfl_xor(md, off));
            if (md == INFINITY) break;
            int kk = (bd == md) ? bi : 0x7FFFFFFF;
#pragma unroll
            for (int off = 32; off; off >>= 1) kk = min(kk, __shfl_xor(kk, off));
            if (lane == round) my_sel = kk;
            if (kk == bi) removed |= 1ull << (bi >> 6);
        }
    }

    if (my_sel >= 0) {
        atomicOr(&adj[(size_t)rg * NW + (my_sel >> 5)], 1u << (my_sel & 31));
        atomicOr(&adj[(size_t)(gbase + my_sel) * NW + (n >> 5)], 1u << (n & 31));
    }
}

// ---------------------------------------------------------------------------
// Kernel 3: build weighted neighbor lists — BARRIER-FREE, ONE WAVE PER ROW
// (4 independent waves per 256-thread block, zero __syncthreads).
// Per wave: uint2 adjacency read (lane l owns m in [64l,64l+64) -> ascending
// deterministic compaction), wave shfl_up prefix, q row staged to a 5-stride
// padded per-wave LDS area (2-way banks = free), then the 16-lane-group
// bf16 cosine gather (4 neighbors concurrently), wave-local sum/normalize,
// and the fused softmax-moments mu0 on lanes 0..31.
__global__ __launch_bounds__(256) void build_kernel(const unsigned short* __restrict__ fnbf,
                             const float4* __restrict__ centers4,
                             const unsigned* __restrict__ adj,
                             uint2* __restrict__ nbr,
                             int* __restrict__ nbr_cnt,
                             const float* __restrict__ raw_sigma,
                             const float* __restrict__ logits,
                             float2* __restrict__ mu0) {
    const int t = threadIdx.x;
    const int lane = t & 63;
    const int wv = t >> 6;          // 0..3
    const int r = blockIdx.x * 4 + wv;
    const int base = r - (r & (N - 1));

    __shared__ float4 s_q[4][16 * 5];   // per-wave padded Q: idx 5e+s (+1 pad/e)
    __shared__ int    s_list[4][CAP];
    __shared__ float  s_w[4][CAP];

    // ---- adjacency compaction (wave-local, ascending => deterministic) ----
    uint2 wpair = *reinterpret_cast<const uint2*>(adj + (size_t)r * NW + 2 * lane);
    const int pc = __popc(wpair.x) + __popc(wpair.y);
    int sc = pc;
#pragma unroll
    for (int off = 1; off < 64; off <<= 1) {
        int o = __shfl_up(sc, off);
        if (lane >= off) sc += o;
    }
    const int total = __shfl(sc, 63);
    const int cnt = total > CAP ? CAP : total;
    int o = sc - pc;                   // exclusive prefix
    {
        unsigned ww = wpair.x; int mb = lane * 64;
        while (ww) { int b = __ffs(ww) - 1; if (o < CAP) s_list[wv][o] = mb + b; ++o; ww &= ww - 1; }
        ww = wpair.y; mb = lane * 64 + 32;
        while (ww) { int b = __ffs(ww) - 1; if (o < CAP) s_list[wv][o] = mb + b; ++o; ww &= ww - 1; }
    }

    // ---- stage q row (bf16 -> f32) into padded per-wave layout ----
    {
        uint2 qw = *reinterpret_cast<const uint2*>(fnbf + (size_t)r * D + 4 * lane);
        float4 qv = make_float4(bflo(qw.x), bfhi(qw.x), bflo(qw.y), bfhi(qw.y));
        const int e = (lane & 31) >> 1;
        const int s = ((lane >> 5) << 1) | (lane & 1);
        s_q[wv][5 * e + s] = qv;       // elems: s0=[8e,8e+4) s1=[8e+4,8e+8) s2=[128+8e..) s3=...
    }

    const float rs = raw_sigma[0];
    const float sigma = fmaxf(log1pf(expf(rs)), 1e-6f);
    const float nhalf_inv_s2 = -0.5f / (sigma * sigma);
    const float4 cq = centers4[r];
    const uint4* fn4 = reinterpret_cast<const uint4*>(fnbf);

    // ---- gather: 16-lane groups, 4 neighbors per wave per step ----
    {
        const int g = lane >> 4;    // neighbor slot (0..3)
        const int e = lane & 15;    // element slice (0..15)
        for (int i0 = 0; i0 < cnt; i0 += 4) {
            const int i = i0 + g;
            const bool act = (i < cnt);
            const int gm = base + s_list[wv][act ? i : 0];
            uint4 a = fn4[(size_t)gm * 32 + e];        // elems [8e, 8e+8)
            uint4 b = fn4[(size_t)gm * 32 + 16 + e];   // elems [128+8e, 128+8e+8)
            float4 cm = centers4[gm];                  // broadcast within group
            float4 qa0 = s_q[wv][5 * e + 0], qa1 = s_q[wv][5 * e + 1];
            float4 qb0 = s_q[wv][5 * e + 2], qb1 = s_q[wv][5 * e + 3];
            float p = bflo(a.x) * qa0.x + bfhi(a.x) * qa0.y
                    + bflo(a.y) * qa0.z + bfhi(a.y) * qa0.w
                    + bflo(a.z) * qa1.x + bfhi(a.z) * qa1.y
                    + bflo(a.w) * qa1.z + bfhi(a.w) * qa1.w
                    + bflo(b.x) * qb0.x + bfhi(b.x) * qb0.y
                    + bflo(b.y) * qb0.z + bfhi(b.y) * qb0.w
                    + bflo(b.z) * qb1.x + bfhi(b.z) * qb1.y
                    + bflo(b.w) * qb1.z + bfhi(b.w) * qb1.w;
#pragma unroll
            for (int off = 1; off < 16; off <<= 1) p += __shfl_xor(p, off);
            float aff = fminf(fmaxf((p + 1.0f) * 0.5f, 0.0f), 1.0f);
            float dist = fmaxf(cq.w + cm.w -
                               2.0f * (cq.x * cm.x + cq.y * cm.y + cq.z * cm.z), 0.0f);
            if (e == 0 && act) s_w[wv][i] = expf(dist * nhalf_inv_s2) * aff;
        }
    }

    // ---- wave-local weight sum (deterministic) + normalize + write ----
    float ps = 0.0f;
    for (int i = lane; i < cnt; i += 64) ps += s_w[wv][i];
#pragma unroll
    for (int off = 32; off; off >>= 1) ps += __shfl_xor(ps, off);
    const float inv_sum = 1.0f / fmaxf(ps, 1e-6f);

    for (int i = lane; i < cnt; i += 64) {
        nbr[(size_t)r * CAP + i] = make_uint2((unsigned)s_list[wv][i],
                                              __float_as_uint(s_w[wv][i] * inv_sum));
    }
    if (lane == 0) nbr_cnt[r] = cnt;

    // ---- fused initial softmax moments (lanes 0..31) ----
    if (lane < C) {
        float x = logits[(size_t)r * C + lane];
        float mx = x;
#pragma unroll
        for (int off = 16; off; off >>= 1) mx = fmaxf(mx, __shfl_xor(mx, off, 32));
        float e = expf(x - mx);
        const float fc = (float)lane;
        float s0 = e, s1 = e * fc, s2 = e * fc * fc;
#pragma unroll
        for (int off = 16; off; off >>= 1) {
            s0 += __shfl_xor(s0, off, 32);
            s1 += __shfl_xor(s1, off, 32);
            s2 += __shfl_xor(s2, off, 32);
        }
        if (lane == 0) mu0[r] = make_float2(s1 / s0, s2 / s0);
    }
}

// ---------------------------------------------------------------------------
// Kernel 4: one mean-field iteration, MOMENT-COMPRESSED (see R9 notes).
__global__ void iter_kernel(const float* __restrict__ logits,
                            const uint2* __restrict__ nbr,
                            const int* __restrict__ nbr_cnt,
                            const float2* __restrict__ mu_in,
                            float2* __restrict__ mu_out,
                            float* __restrict__ out,
                            const float* __restrict__ raw_smooth,
                            int last) {
    const int t = threadIdx.x;
    const int r = blockIdx.x * 8 + (t >> 5);
    const int c = t & 31;
    const int base = r - (r & (N - 1));
    const float smooth = log1pf(expf(raw_smooth[0]));

    const int cnt = nbr_cnt[r];
    const uint2* np = nbr + (size_t)r * CAP;

    float m0 = 0.0f, m1 = 0.0f, m2 = 0.0f;
    for (int j = c; j < cnt; j += 32) {
        uint2 e = np[j];
        float w = __uint_as_float(e.y);
        float2 mu = mu_in[base + (int)e.x];
        m0 += w;
        m1 += w * mu.x;
        m2 += w * mu.y;
    }
#pragma unroll
    for (int off = 16; off; off >>= 1) {
        m0 += __shfl_xor(m0, off, 32);
        m1 += __shfl_xor(m1, off, 32);
        m2 += __shfl_xor(m2, off, 32);
    }

    const float fc = (float)c;
    float pw = (m2 - 2.0f * fc * m1 + fc * fc * m0) * (1.0f / 961.0f);
    float refined = logits[(size_t)r * C + c] - smooth * pw;

    if (last) {
        out[(size_t)r * C + c] = refined;
        return;
    }

    float mx = refined;
#pragma unroll
    for (int off = 16; off; off >>= 1) mx = fmaxf(mx, __shfl_xor(mx, off, 32));
    float e = expf(refined - mx);
    float s0 = e, s1 = e * fc, s2 = e * fc * fc;
#pragma unroll
    for (int off = 16; off; off >>= 1) {
        s0 += __shfl_xor(s0, off, 32);
        s1 += __shfl_xor(s1, off, 32);
        s2 += __shfl_xor(s2, off, 32);
    }
    if (c == 0) mu_out[r] = make_float2(s1 / s0, s2 / s0);
}

// ---------------------------------------------------------------------------
extern "C" void kernel_launch(void* const* d_in, const int* in_sizes, int n_in,
                              void* d_out, int out_size, void* d_ws, size_t ws_size,
                              hipStream_t stream) {
    const float* logits     = (const float*)d_in[0];
    const float* rois       = (const float*)d_in[1];
    const float* feats      = (const float*)d_in[2];
    const float* raw_sigma  = (const float*)d_in[3];
    const float* raw_smooth = (const float*)d_in[4];
    float* out = (float*)d_out;

    char* ws = (char*)d_ws;
    size_t off = 0;
    auto alloc = [&](size_t bytes) -> void* {
        void* p = ws + off;
        off += (bytes + 255) & ~(size_t)255;
        return p;
    };
    float4*         centers4 = (float4*)        alloc((size_t)ROWS * sizeof(float4));
    unsigned short* fnbf     = (unsigned short*)alloc((size_t)ROWS * D * 2);
    unsigned*       adj      = (unsigned*)      alloc((size_t)ROWS * NW * 4);
    uint2*          nbr      = (uint2*)         alloc((size_t)ROWS * CAP * 8);
    int*            nbr_cnt  = (int*)           alloc((size_t)ROWS * 4);
    float2*         mu_a     = (float2*)        alloc((size_t)ROWS * 8);
    float2*         mu_b     = (float2*)        alloc((size_t)ROWS * 8);

    pre_kernel<<<ROWS / 4, 256, 0, stream>>>(rois, feats, centers4, fnbf, (uint2*)adj);
    knn_kernel<<<ROWS / 16, 1024, 0, stream>>>(centers4, adj);
    build_kernel<<<ROWS / 4, 256, 0, stream>>>(fnbf, centers4, adj,
                                               nbr, nbr_cnt, raw_sigma, logits, mu_a);

    float2* mi = mu_a;
    float2* mo = mu_b;
    for (int it = 0; it < 5; ++it) {
        iter_kernel<<<ROWS / 8, 256, 0, stream>>>(logits, nbr, nbr_cnt,
                                                  mi, mo, out, raw_smooth,
                                                  (it == 4) ? 1 : 0);
        float2* tmp = mi; mi = mo; mo = tmp;
    }
}